// Round 22
// baseline (218.825 us; speedup 1.0000x reference)
//
#include <hip/hip_runtime.h>

#define NPOS 1024
#define BB   32
#define SS   1024
#define ALPHA_C 0.3f
#define OCAP 256      // per-batch overflow capacity per side (mean ~3.7, P(>256)~0)
#define MAXO 16       // overflow entries/batch/side processed by fixup
#define PADPAIR 0x10001000u   // two packed PRE-SHIFTED pads (byte off 4096 = zero slot)
#define NZ4 16656             // uint4s in the zero region (rcnt+scnt+bmask+ocnt*)
#define NP4 16384             // uint4s in ell16 (PADPAIR init)

typedef float    __attribute__((ext_vector_type(2))) f32x2;
typedef float    __attribute__((ext_vector_type(4))) f32x4;
typedef int      __attribute__((ext_vector_type(4))) i32x4;
typedef unsigned __attribute__((ext_vector_type(4))) u32x4;

// ---- K0: one fill kernel: zeros the counter region, PADPAIR-inits the ELL ----
__global__ __launch_bounds__(256) void fill_tables(u32x4* __restrict__ z,
                                                   u32x4* __restrict__ p) {
    const int i = blockIdx.x * 256 + threadIdx.x;
    if (i < NZ4) z[i] = (u32x4){0u, 0u, 0u, 0u};
    else { const int j = i - NZ4; if (j < NP4) p[j] = (u32x4){PADPAIR, PADPAIR, PADPAIR, PADPAIR}; }
}

// ---- K1: whole-chip build (128 blocks x 256): per-(r,b) row lists (W=4 + ovf)
// and per-batch 16-bit column ELL (W=4 + ovf), via global-atomic counters. ----
__global__ __launch_bounds__(256) void build_tables(
    const int* __restrict__ adds, unsigned* __restrict__ rcnt,
    unsigned* __restrict__ scnt, unsigned* __restrict__ bmask,
    ushort* __restrict__ list, ushort* __restrict__ ell16,
    int* __restrict__ ocntc, int* __restrict__ ocntr,
    int* __restrict__ oentc, int* __restrict__ oentr) {
    const int b  = blockIdx.x >> 2;
    const int tg = ((blockIdx.x & 3) << 8) | threadIdx.x;   // p1 / p2 position
    const int c  = adds[b * SS + tg];
    // column side (pre-shifted byte offsets)
    const unsigned slot = atomicAdd(&scnt[b * NPOS + c], 1u);
    if (slot < 4u) {
        ell16[(((size_t)b * 512 + (c & 511)) * 2 + (c >> 9)) * 4 + slot] = (ushort)(tg << 2);
    } else {
        const int o = atomicAdd(&ocntc[b], 1);
        if (o < OCAP) oentc[b * OCAP + o] = (c << 10) | tg;
    }
    // row side (per-(r,b) W=4 list)
    const unsigned rs = atomicAdd(&rcnt[c * BB + b], 1u);
    if (rs < 4u) {
        list[(size_t)c * 128 + b * 4 + rs] = (ushort)tg;
    } else {
        const int o = atomicAdd(&ocntr[b], 1);
        if (o < OCAP) oentr[b * OCAP + o] = (c << 10) | tg;
        atomicOr(&bmask[b * 32 + (tg >> 5)], 1u << (tg & 31));
    }
}

// ---- K2: WAVE-SYNCHRONOUS hist rows. Block = row r, 4 waves; wave w owns
// active batches j==w (mod 4) and ALL 1024 columns (lane l: col-pairs
// l+64p, p=0..7). Each wave stages S into its PRIVATE LDS buffer and
// scatters it with NO barriers (same-wave LDS ops are pipeline-ordered;
// compiler inserts exact vmcnt/lgkm waits). Depth-2 row prefetch via
// RA/RB ping-pong (loop unrolled x2 -> no register copies). One final
// __syncthreads + 4-way reduce writes the raw row. ----
#define HR_BODY(I, RR, EE, MM)                                              \
  do {                                                                      \
    /* S-write item I from RR (MM rows summed in registers) */              \
    _Pragma("unroll")                                                       \
    for (int k = 0; k < 8; ++k) {                                           \
      f32x2 Sv = RR[0][k];                                                  \
      if (MM > 1) Sv += RR[1][k];                                           \
      if (MM > 2) Sv += RR[2][k];                                           \
      if (MM > 3) Sv += RR[3][k];                                           \
      ((f32x2*)Sbuf)[l + 64 * k] = Sv;                                      \
    }                                                                       \
    /* issue HBM row loads for item I+2 into RR (registers just freed) */   \
    if ((I) + 2 < nah) {                                                    \
      const int b2_ = actb_s[w + 4 * ((I) + 2)];                            \
      MM = mcnt_s[b2_];                                                     \
      _Pragma("unroll")                                                     \
      for (int s = 0; s < 4; ++s)                                           \
        if (MM > s) {                                                       \
          const f32x2* rp_ = (const f32x2*)(a +                             \
              ((((size_t)b2_ << 10) + lsrc[b2_ * 4 + s]) << 10));           \
          _Pragma("unroll")                                                 \
          for (int k = 0; k < 8; ++k)                                       \
            RR[s][k] = __builtin_nontemporal_load(rp_ + l + 64 * k);        \
        }                                                                   \
    } else { MM = 0; }                                                      \
    __builtin_amdgcn_sched_barrier(0);                                      \
    /* scatter item I (ds_reads queue in-order behind the S-writes) */      \
    {                                                                       \
      const char* rb_ = (const char*)Sbuf;                                  \
      _Pragma("unroll")                                                     \
      for (int p = 0; p < 8; ++p) {                                         \
        acc0[p] += *(const float*)(rb_ + (EE[p].x & 0xffffu));              \
        acc0[p] += *(const float*)(rb_ + (EE[p].x >> 16));                  \
        acc0[p] += *(const float*)(rb_ + (EE[p].y & 0xffffu));              \
        acc0[p] += *(const float*)(rb_ + (EE[p].y >> 16));                  \
        acc1[p] += *(const float*)(rb_ + (EE[p].z & 0xffffu));              \
        acc1[p] += *(const float*)(rb_ + (EE[p].z >> 16));                  \
        acc1[p] += *(const float*)(rb_ + (EE[p].w & 0xffffu));              \
        acc1[p] += *(const float*)(rb_ + (EE[p].w >> 16));                  \
      }                                                                     \
    }                                                                       \
    /* reload EE for item I+2 (L2-hot, two-item lead) */                    \
    if ((I) + 2 < nah) {                                                    \
      const int b2e_ = actb_s[w + 4 * ((I) + 2)];                           \
      _Pragma("unroll")                                                     \
      for (int p = 0; p < 8; ++p)                                           \
        EE[p] = ellv[(size_t)b2e_ * 512 + l + 64 * p];                      \
    }                                                                       \
  } while (0)

__global__ __launch_bounds__(256, 2) void hist_rows_kernel(
    const float* __restrict__ a, const unsigned* __restrict__ rcnt,
    const ushort* __restrict__ list, const ushort* __restrict__ ell16,
    float* __restrict__ hist) {
    __shared__ float Sall[4][1026];    // per-wave buffer; [1024] = zero slot
    __shared__ ushort lsrc[128];
    __shared__ int mcnt_s[32];
    __shared__ ushort actb_s[32];
    __shared__ int na_s;
    const int r = blockIdx.x, t = threadIdx.x;
    const int w = t >> 6, l = t & 63;
    float* Sbuf = &Sall[w][0];

    if (t < 128) lsrc[t] = list[(size_t)r * 128 + t];
    if (t < 32)  mcnt_s[t] = min((int)rcnt[r * BB + t], 4);
    if (l == 0)  Sall[w][1024] = 0.f;    // pad target (wave-private)
    __syncthreads();
    if (t == 0) {
        int na = 0;
        for (int b = 0; b < 32; ++b) if (mcnt_s[b]) actb_s[na++] = (ushort)b;
        na_s = na;
    }
    __syncthreads();
    const int na  = na_s;
    const int nah = (na > w) ? ((na - w + 3) >> 2) : 0;   // my items: j = w + 4i
    const u32x4* ellv = (const u32x4*)ell16;

    float acc0[8], acc1[8];
    #pragma unroll
    for (int p = 0; p < 8; ++p) { acc0[p] = 0.f; acc1[p] = 0.f; }

    u32x4 EA[8], EB[8];
    f32x2 RA[4][8], RB[4][8];
    int m0v = 0, m1v = 0;

    if (nah > 0) {                       // prologue: items 0 and 1
        const int b0 = actb_s[w];
        m0v = mcnt_s[b0];
        #pragma unroll
        for (int p = 0; p < 8; ++p) EA[p] = ellv[(size_t)b0 * 512 + l + 64 * p];
        #pragma unroll
        for (int s = 0; s < 4; ++s)
            if (m0v > s) {
                const f32x2* rp = (const f32x2*)(a + ((((size_t)b0 << 10) + lsrc[b0 * 4 + s]) << 10));
                #pragma unroll
                for (int k = 0; k < 8; ++k) RA[s][k] = __builtin_nontemporal_load(rp + l + 64 * k);
            }
    }
    if (nah > 1) {
        const int b1 = actb_s[w + 4];
        m1v = mcnt_s[b1];
        #pragma unroll
        for (int p = 0; p < 8; ++p) EB[p] = ellv[(size_t)b1 * 512 + l + 64 * p];
        #pragma unroll
        for (int s = 0; s < 4; ++s)
            if (m1v > s) {
                const f32x2* rp = (const f32x2*)(a + ((((size_t)b1 << 10) + lsrc[b1 * 4 + s]) << 10));
                #pragma unroll
                for (int k = 0; k < 8; ++k) RB[s][k] = __builtin_nontemporal_load(rp + l + 64 * k);
            }
    }

    int i = 0;
    for (; i + 1 < nah; i += 2) {        // NO barriers in this loop
        HR_BODY(i,     RA, EA, m0v);
        HR_BODY(i + 1, RB, EB, m1v);
    }
    if (i < nah) HR_BODY(i, RA, EA, m0v);

    // write per-wave partials into own buffer, then 4-way reduce
    #pragma unroll
    for (int p = 0; p < 8; ++p) {
        Sbuf[l + 64 * p]       = acc0[p];
        Sbuf[l + 64 * p + 512] = acc1[p];
    }
    __syncthreads();
    #pragma unroll
    for (int q = 0; q < 4; ++q) {
        const int col = (q << 8) + t;
        hist[(size_t)r * NPOS + col] =
            Sall[0][col] + Sall[1][col] + Sall[2][col] + Sall[3][col];
    }
}

// ---- K2b: fixups via global atomics AFTER hist_rows (raw domain).
// Grid (BB, 2*MAXO); the 1024 p-positions are a 4-iter thread loop. ----
__global__ __launch_bounds__(256) void fixup(
    const float* __restrict__ a, const int* __restrict__ adds,
    const int* __restrict__ ocntc, const int* __restrict__ oentc,
    const int* __restrict__ ocntr, const int* __restrict__ oentr,
    const unsigned* __restrict__ bmask, float* __restrict__ hist) {
    const int b = blockIdx.x;
    int y = blockIdx.y;
    if (y < MAXO) {                    // column overflow: p is p1
        if (y >= ocntc[b]) return;
        const int e = oentc[b * OCAP + y];
        const int c = e >> 10, p2 = e & 1023;
        #pragma unroll
        for (int z = 0; z < 4; ++z) {
            const int p = (z << 8) + threadIdx.x;
            if ((bmask[b * 32 + (p >> 5)] >> (p & 31)) & 1u) continue;  // row-ovf p1 excluded
            const int r = adds[b * SS + p];
            atomicAdd(&hist[(size_t)r * NPOS + c], a[((size_t)(b * SS + p)) * SS + p2]);
        }
    } else {                           // row overflow: p is p2
        y -= MAXO;
        if (y >= ocntr[b]) return;
        const int e = oentr[b * OCAP + y];
        const int r = e >> 10, p1 = e & 1023;
        #pragma unroll
        for (int z = 0; z < 4; ++z) {
            const int p = (z << 8) + threadIdx.x;
            const int c = adds[b * SS + p];
            atomicAdd(&hist[(size_t)r * NPOS + c], a[((size_t)(b * SS + p1)) * SS + p]);
        }
    }
}

// ---- K3: out = s + 0.3 * sigmoid(score_row[pos[b,p2]]), score row staged
// in LDS (base wave-uniform per block). ----
__global__ __launch_bounds__(256) void gather_kernel(
    const float* __restrict__ s, const int* __restrict__ pos,
    const float* __restrict__ score, float* __restrict__ out) {
    __shared__ float srow[NPOS];
    const int row = blockIdx.x;
    const int b   = row >> 10;
    const int*  posb = pos + b * SS;
    const int   base = posb[row & 1023] * NPOS;
    const size_t off = (size_t)row * SS;
    const int t = threadIdx.x;

    const f32x4 sc = ((const f32x4*)(score + base))[t];
    f32x4 v = __builtin_nontemporal_load(((const f32x4*)(s + off)) + t);
    i32x4 c = ((const i32x4*)posb)[t];
    ((f32x4*)srow)[t] = sc;
    __syncthreads();

    const float h0 = srow[c.x], h1 = srow[c.y];
    const float h2 = srow[c.z], h3 = srow[c.w];
    f32x4 o;
    o.x = v.x + ALPHA_C * (1.f / (1.f + __expf(-h0)));
    o.y = v.y + ALPHA_C * (1.f / (1.f + __expf(-h1)));
    o.z = v.z + ALPHA_C * (1.f / (1.f + __expf(-h2)));
    o.w = v.w + ALPHA_C * (1.f / (1.f + __expf(-h3)));
    __builtin_nontemporal_store(o, ((f32x4*)(out + off)) + t);
}

extern "C" void kernel_launch(void* const* d_in, const int* in_sizes, int n_in,
                              void* d_out, int out_size, void* d_ws, size_t ws_size,
                              hipStream_t stream) {
    const float* s_arc = (const float*)d_in[0];
    const float* a_arc = (const float*)d_in[1];
    const int*   adds  = (const int*)d_in[2];
    const int*   pos   = (const int*)d_in[3];
    float* out  = (float*)d_out;

    // ws layout (bytes):
    // [hist 4MB][rcnt 128K][scnt 128K][bmask 4K][ocntc 128][ocntr 128]
    // [list 256K][ell16 256K][oentc 32K][oentr 32K]  (~4.83MB)
    char* w = (char*)d_ws;
    float*    hist  = (float*)w;                 w += (size_t)NPOS * NPOS * 4;
    unsigned* rcnt  = (unsigned*)w;              w += (size_t)NPOS * BB * 4;
    unsigned* scnt  = (unsigned*)w;              w += (size_t)BB * NPOS * 4;
    unsigned* bmask = (unsigned*)w;              w += (size_t)BB * 32 * 4;
    int*      ocntc = (int*)w;                   w += BB * 4;
    int*      ocntr = (int*)w;                   w += BB * 4;
    ushort*   list  = (ushort*)w;                w += (size_t)NPOS * 128 * 2;
    ushort*   ell16 = (ushort*)w;                w += (size_t)BB * NPOS * 4 * 2;
    int*      oentc = (int*)w;                   w += (size_t)BB * OCAP * 4;
    int*      oentr = (int*)w;

    fill_tables<<<(NZ4 + NP4 + 255) / 256, 256, 0, stream>>>((u32x4*)rcnt, (u32x4*)ell16);
    build_tables<<<4 * BB, 256, 0, stream>>>(adds, rcnt, scnt, bmask, list, ell16,
                                             ocntc, ocntr, oentc, oentr);
    hist_rows_kernel<<<NPOS, 256, 0, stream>>>(a_arc, rcnt, list, ell16, hist);
    fixup<<<dim3(BB, 2 * MAXO), 256, 0, stream>>>(a_arc, adds, ocntc, oentc,
                                                  ocntr, oentr, bmask, hist);
    gather_kernel<<<BB * SS, 256, 0, stream>>>(s_arc, pos, hist, out);
}

// Round 23
// 116.227 us; speedup vs baseline: 1.8827x; 1.8827x over previous
//
#include <hip/hip_runtime.h>

#define NPOS 1024
#define BB   32
#define SS   1024
#define ALPHA_C 0.3f
#define OCAP 256      // per-batch overflow capacity per side (mean ~3.7, P(>256)~0)
#define MAXO 16       // overflow entries/batch/side processed by fixup
#define PADPAIR 0x10001000u   // two packed PRE-SHIFTED pads (byte off 4096 = zero slot)
#define SSTRIDE 1026          // floats per S row: 1024 data + zero slot @ [1024] + align
#define NZ4 16656             // uint4s in the zero region (rcnt+scnt+bmask+ocnt*)
#define NP4 16384             // uint4s in ell16 (PADPAIR init)

typedef float    __attribute__((ext_vector_type(2))) f32x2;
typedef float    __attribute__((ext_vector_type(4))) f32x4;
typedef int      __attribute__((ext_vector_type(4))) i32x4;
typedef unsigned __attribute__((ext_vector_type(4))) u32x4;

// ---- K0: one fill kernel: zeros the counter region, PADPAIR-inits the ELL ----
__global__ __launch_bounds__(256) void fill_tables(u32x4* __restrict__ z,
                                                   u32x4* __restrict__ p) {
    const int i = blockIdx.x * 256 + threadIdx.x;
    if (i < NZ4) z[i] = (u32x4){0u, 0u, 0u, 0u};
    else { const int j = i - NZ4; if (j < NP4) p[j] = (u32x4){PADPAIR, PADPAIR, PADPAIR, PADPAIR}; }
}

// ---- K1: whole-chip build (128 blocks x 256): per-(r,b) row lists (W=4 + ovf)
// and per-batch 16-bit column ELL (W=4 + ovf), via global-atomic counters. ----
__global__ __launch_bounds__(256) void build_tables(
    const int* __restrict__ adds, unsigned* __restrict__ rcnt,
    unsigned* __restrict__ scnt, unsigned* __restrict__ bmask,
    ushort* __restrict__ list, ushort* __restrict__ ell16,
    int* __restrict__ ocntc, int* __restrict__ ocntr,
    int* __restrict__ oentc, int* __restrict__ oentr) {
    const int b  = blockIdx.x >> 2;
    const int tg = ((blockIdx.x & 3) << 8) | threadIdx.x;   // p1 / p2 position
    const int c  = adds[b * SS + tg];
    // column side (pre-shifted byte offsets)
    const unsigned slot = atomicAdd(&scnt[b * NPOS + c], 1u);
    if (slot < 4u) {
        ell16[(((size_t)b * 512 + (c & 511)) * 2 + (c >> 9)) * 4 + slot] = (ushort)(tg << 2);
    } else {
        const int o = atomicAdd(&ocntc[b], 1);
        if (o < OCAP) oentc[b * OCAP + o] = (c << 10) | tg;
    }
    // row side (per-(r,b) W=4 list)
    const unsigned rs = atomicAdd(&rcnt[c * BB + b], 1u);
    if (rs < 4u) {
        list[(size_t)c * 128 + b * 4 + rs] = (ushort)tg;
    } else {
        const int o = atomicAdd(&ocntr[b], 1);
        if (o < OCAP) oentr[b * OCAP + o] = (c << 10) | tg;
        atomicOr(&bmask[b * 32 + (tg >> 5)], 1u << (tg & 31));
    }
}

// ---- K2: block per hist row r; iterate ACTIVE batches (~20 of 32).
// DEPTH-3 row pipeline: rows for batch j+3 issued at iter j, consumed at
// j+2's S-write (~1200cy lead > 900cy HBM latency). Pre-sum <=4 rows in
// registers, ds_write ONE combined row S, scatter once via column ELL.
// Writes RAW sums (fixup adds after; gather applies sigmoid). ----
__global__ __launch_bounds__(512) void hist_rows_kernel(
    const float* __restrict__ a, const unsigned* __restrict__ rcnt,
    const ushort* __restrict__ list, const ushort* __restrict__ ell16,
    float* __restrict__ hist) {
    __shared__ float Sbuf[2][SSTRIDE];   // [..][1024] = 0.0f pad slot
    __shared__ ushort lsrc[128];
    __shared__ int   mcnt_s[32];
    __shared__ ushort actb_s[32];
    __shared__ int   na_s;
    const int r = blockIdx.x, t = threadIdx.x;

    if (t < 128) lsrc[t] = list[(size_t)r * 128 + t];
    if (t < 32)  mcnt_s[t] = min((int)rcnt[r * BB + t], 4);
    if (t < 2)   Sbuf[t][1024] = 0.f;
    __syncthreads();
    if (t == 0) {
        int na = 0;
        for (int b = 0; b < 32; ++b) if (mcnt_s[b]) actb_s[na++] = (ushort)b;
        na_s = na;
    }
    __syncthreads();
    const int na = na_s;
    const u32x4* ellv = (const u32x4*)ell16;
    float acc0 = 0.f, acc1 = 0.f;
    u32x4 E = (u32x4){PADPAIR, PADPAIR, PADPAIR, PADPAIR}, F = E;
    f32x2 R0 = (f32x2){0.f, 0.f}, R1 = R0, R2 = R0, R3 = R0;   // batch j+1 rows
    f32x2 T0 = R0, T1 = R0, T2 = R0, T3 = R0;                  // batch j+2 rows
    int mR = 0, mT = 0;

#define ROWP(bb, s) ((const f32x2*)(a + ((((size_t)(bb) << 10) + lsrc[(bb) * 4 + (s)]) << 10)) + t)

    if (na > 0) {
        const int b0 = actb_s[0], m0 = mcnt_s[b0];
        E = ellv[(size_t)b0 * 512 + t];
        f32x2 S = __builtin_nontemporal_load(ROWP(b0, 0));
        if (m0 > 1) S += __builtin_nontemporal_load(ROWP(b0, 1));
        if (m0 > 2) S += __builtin_nontemporal_load(ROWP(b0, 2));
        if (m0 > 3) S += __builtin_nontemporal_load(ROWP(b0, 3));
        ((f32x2*)&Sbuf[0][0])[t] = S;
        if (na > 1) {
            const int b1 = actb_s[1];
            mR = mcnt_s[b1];
            F = ellv[(size_t)b1 * 512 + t];
            R0 = __builtin_nontemporal_load(ROWP(b1, 0));
            if (mR > 1) R1 = __builtin_nontemporal_load(ROWP(b1, 1));
            if (mR > 2) R2 = __builtin_nontemporal_load(ROWP(b1, 2));
            if (mR > 3) R3 = __builtin_nontemporal_load(ROWP(b1, 3));
        }
        if (na > 2) {
            const int b2 = actb_s[2];
            mT = mcnt_s[b2];
            T0 = __builtin_nontemporal_load(ROWP(b2, 0));
            if (mT > 1) T1 = __builtin_nontemporal_load(ROWP(b2, 1));
            if (mT > 2) T2 = __builtin_nontemporal_load(ROWP(b2, 2));
            if (mT > 3) T3 = __builtin_nontemporal_load(ROWP(b2, 3));
        }
    }
    asm volatile("s_waitcnt lgkmcnt(0)" ::: "memory");
    __builtin_amdgcn_s_barrier();

    for (int j = 0; j < na; ++j) {
        // issue row loads for batch j+3 (two full iterations to land)
        f32x2 U0 = (f32x2){0.f, 0.f}, U1 = U0, U2 = U0, U3 = U0;
        int mU = 0;
        if (j + 3 < na) {
            const int b3 = actb_s[j + 3];
            mU = mcnt_s[b3];
            U0 = __builtin_nontemporal_load(ROWP(b3, 0));
            if (mU > 1) U1 = __builtin_nontemporal_load(ROWP(b3, 1));
            if (mU > 2) U2 = __builtin_nontemporal_load(ROWP(b3, 2));
            if (mU > 3) U3 = __builtin_nontemporal_load(ROWP(b3, 3));
        }
        // ELL indices for batch j+2 (consumed at scatter in iter j+2)
        u32x4 TE = (u32x4){PADPAIR, PADPAIR, PADPAIR, PADPAIR};
        if (j + 2 < na) TE = ellv[(size_t)actb_s[j + 2] * 512 + t];
        // pre-sum & write S for batch j+1 (rows issued at iter j-2: ~1200cy lead)
        if (j + 1 < na) {
            f32x2 S = R0;
            if (mR > 1) S += R1;
            if (mR > 2) S += R2;
            if (mR > 3) S += R3;
            ((f32x2*)&Sbuf[(j + 1) & 1][0])[t] = S;
        }
        // scatter batch j from Sbuf[j&1] (8 LDS reads/thread, pre-shifted offsets)
        const char* rb = (const char*)&Sbuf[j & 1][0];
        acc0 += *(const float*)(rb + (E.x & 0xffffu));
        acc0 += *(const float*)(rb + (E.x >> 16));
        acc0 += *(const float*)(rb + (E.y & 0xffffu));
        acc0 += *(const float*)(rb + (E.y >> 16));
        acc1 += *(const float*)(rb + (E.z & 0xffffu));
        acc1 += *(const float*)(rb + (E.z >> 16));
        acc1 += *(const float*)(rb + (E.w & 0xffffu));
        acc1 += *(const float*)(rb + (E.w >> 16));
        // roll pipeline
        E = F; F = TE;
        R0 = T0; R1 = T1; R2 = T2; R3 = T3; mR = mT;
        T0 = U0; T1 = U1; T2 = U2; T3 = U3; mT = mU;
        __builtin_amdgcn_sched_barrier(0);
        asm volatile("s_waitcnt lgkmcnt(0)" ::: "memory");
        __builtin_amdgcn_s_barrier();
    }
#undef ROWP

    const size_t o0 = (size_t)r * NPOS + t;
    hist[o0]       = acc0;     // RAW sums; fixup atomics add after; gather sigmoids
    hist[o0 + 512] = acc1;
}

// ---- K2b: fixups via global atomics AFTER hist_rows (raw domain).
// y<MAXO: col-ovf entry (all p1 EXCEPT row-ovf p1); y>=MAXO: row-ovf (all p2). ----
__global__ __launch_bounds__(256) void fixup(
    const float* __restrict__ a, const int* __restrict__ adds,
    const int* __restrict__ ocntc, const int* __restrict__ oentc,
    const int* __restrict__ ocntr, const int* __restrict__ oentr,
    const unsigned* __restrict__ bmask, float* __restrict__ hist) {
    const int b = blockIdx.x;
    int y = blockIdx.y;
    const int p = blockIdx.z * 256 + threadIdx.x;
    if (y < MAXO) {                    // column overflow: p is p1
        if (y >= ocntc[b]) return;
        const int e = oentc[b * OCAP + y];
        const int c = e >> 10, p2 = e & 1023;
        if ((bmask[b * 32 + (p >> 5)] >> (p & 31)) & 1u) return;  // row-ovf p1 excluded
        const int r = adds[b * SS + p];
        atomicAdd(&hist[(size_t)r * NPOS + c], a[((size_t)(b * SS + p)) * SS + p2]);
    } else {                           // row overflow: p is p2
        y -= MAXO;
        if (y >= ocntr[b]) return;
        const int e = oentr[b * OCAP + y];
        const int r = e >> 10, p1 = e & 1023;
        const int c = adds[b * SS + p];
        atomicAdd(&hist[(size_t)r * NPOS + c], a[((size_t)(b * SS + p1)) * SS + p]);
    }
}

// ---- K3: out = s + 0.3 * sigmoid(score_row[pos[b,p2]]), score row staged in
// LDS: base = pos[b,p1]*1024 is WAVE-UNIFORM per block, so 4 coalesced wave
// loads stage the 4KB row; the 4 random reads/thread then hit LDS (~10cy)
// instead of serialized L1 gathers (~64cy/wave-instr). ----
__global__ __launch_bounds__(256) void gather_kernel(
    const float* __restrict__ s, const int* __restrict__ pos,
    const float* __restrict__ score, float* __restrict__ out) {
    __shared__ float srow[NPOS];
    const int row = blockIdx.x;
    const int b   = row >> 10;
    const int*  posb = pos + b * SS;
    const int   base = posb[row & 1023] * NPOS;
    const size_t off = (size_t)row * SS;
    const int t = threadIdx.x;

    // stage the score row (coalesced, L2/L3-hot) + issue stream loads
    const f32x4 sc = ((const f32x4*)(score + base))[t];
    f32x4 v = __builtin_nontemporal_load(((const f32x4*)(s + off)) + t);
    i32x4 c = ((const i32x4*)posb)[t];
    ((f32x4*)srow)[t] = sc;
    __syncthreads();

    const float h0 = srow[c.x], h1 = srow[c.y];
    const float h2 = srow[c.z], h3 = srow[c.w];
    f32x4 o;
    o.x = v.x + ALPHA_C * (1.f / (1.f + __expf(-h0)));
    o.y = v.y + ALPHA_C * (1.f / (1.f + __expf(-h1)));
    o.z = v.z + ALPHA_C * (1.f / (1.f + __expf(-h2)));
    o.w = v.w + ALPHA_C * (1.f / (1.f + __expf(-h3)));
    __builtin_nontemporal_store(o, ((f32x4*)(out + off)) + t);
}

extern "C" void kernel_launch(void* const* d_in, const int* in_sizes, int n_in,
                              void* d_out, int out_size, void* d_ws, size_t ws_size,
                              hipStream_t stream) {
    const float* s_arc = (const float*)d_in[0];
    const float* a_arc = (const float*)d_in[1];
    const int*   adds  = (const int*)d_in[2];
    const int*   pos   = (const int*)d_in[3];
    float* out  = (float*)d_out;

    // ws layout (bytes):
    // [hist 4MB][rcnt 128K][scnt 128K][bmask 4K][ocntc 128][ocntr 128]
    // [list 256K][ell16 256K][oentc 32K][oentr 32K]  (~4.83MB)
    char* w = (char*)d_ws;
    float*    hist  = (float*)w;                 w += (size_t)NPOS * NPOS * 4;
    unsigned* rcnt  = (unsigned*)w;              w += (size_t)NPOS * BB * 4;
    unsigned* scnt  = (unsigned*)w;              w += (size_t)BB * NPOS * 4;
    unsigned* bmask = (unsigned*)w;              w += (size_t)BB * 32 * 4;
    int*      ocntc = (int*)w;                   w += BB * 4;
    int*      ocntr = (int*)w;                   w += BB * 4;
    ushort*   list  = (ushort*)w;                w += (size_t)NPOS * 128 * 2;
    ushort*   ell16 = (ushort*)w;                w += (size_t)BB * NPOS * 4 * 2;
    int*      oentc = (int*)w;                   w += (size_t)BB * OCAP * 4;
    int*      oentr = (int*)w;

    fill_tables<<<(NZ4 + NP4 + 255) / 256, 256, 0, stream>>>((u32x4*)rcnt, (u32x4*)ell16);
    build_tables<<<4 * BB, 256, 0, stream>>>(adds, rcnt, scnt, bmask, list, ell16,
                                             ocntc, ocntr, oentc, oentr);
    hist_rows_kernel<<<NPOS, 512, 0, stream>>>(a_arc, rcnt, list, ell16, hist);
    fixup<<<dim3(BB, 2 * MAXO, SS / 256), 256, 0, stream>>>(a_arc, adds, ocntc, oentc,
                                                            ocntr, oentr, bmask, hist);
    gather_kernel<<<BB * SS, 256, 0, stream>>>(s_arc, pos, hist, out);
}